// Round 4
// baseline (33.864 us; speedup 1.0000x reference)
//
#include <hip/hip_runtime.h>

// PointPillarsScatter: canvas[b, :, y, x] = voxel_features[n, :]
// voxel_features (B*N_PER, C) f32, coords (B*N_PER, 4) int32 (bid, 0, y, x)
// Output: (B, C, NY, NX) f32.
//
// Strategy: inverse-index map (pixel -> point id) in workspace, then one
// fully-coalesced gather pass that writes every output element exactly once.
// Each gather thread: 4 pixels x 16 channels -> per occupied pixel one
// contiguous 64B feat read (full cache line, no duplicate fetches).

#define NYc 496
#define NXc 432
#define Cc  64
#define Bc  2
#define NPIX (NYc * NXc)        // 214272, divisible by 4
#define NQ   (NPIX / 4)         // 53568 float4 pixel-groups per plane
#define NIDX4 ((Bc * NPIX) / 4) // 107136 int4s in the idx map

typedef float f32x4 __attribute__((ext_vector_type(4)));
typedef int   i32x4 __attribute__((ext_vector_type(4)));

// Fast idx-map init to -1.
__global__ void pps_init_idx(i32x4* __restrict__ idx4) {
    int i = blockIdx.x * blockDim.x + threadIdx.x;
    if (i < NIDX4) {
        i32x4 m1 = {-1, -1, -1, -1};
        idx4[i] = m1;
    }
}

// Scatter point ids into the per-pixel index map.
__global__ void pps_scatter_idx(const int* __restrict__ coords,
                                int* __restrict__ idx, int n_pts) {
    int n = blockIdx.x * blockDim.x + threadIdx.x;
    if (n >= n_pts) return;
    int bid = coords[n * 4 + 0];
    int y   = coords[n * 4 + 2];
    int x   = coords[n * 4 + 3];
    idx[bid * NPIX + y * NXc + x] = n;
}

// Coalesced gather: each thread handles 4 pixels x 16 channels.
// Per occupied pixel: one contiguous 64B feat read (4x dwordx4).
__global__ void pps_gather16(const float* __restrict__ feat,
                             const int* __restrict__ idx,
                             float* __restrict__ out) {
    int q = blockIdx.x * blockDim.x + threadIdx.x;   // float4 pixel-group
    if (q >= NQ) return;
    int g  = blockIdx.y;                             // 0..7
    int b  = g >> 2;                                 // 4 ch-groups per batch
    int c0 = (g & 3) << 4;                           // 0,16,32,48

    const i32x4 pid4 = *reinterpret_cast<const i32x4*>(idx + (size_t)b * NPIX + (size_t)q * 4);

    f32x4 f[4][4];                                   // [pixel][ch-quad]
    #pragma unroll
    for (int p = 0; p < 4; ++p)
        #pragma unroll
        for (int j = 0; j < 4; ++j)
            f[p][j] = (f32x4){0.f, 0.f, 0.f, 0.f};

    const int pids[4] = {pid4.x, pid4.y, pid4.z, pid4.w};
    #pragma unroll
    for (int p = 0; p < 4; ++p) {
        if (pids[p] >= 0) {
            const f32x4* row = reinterpret_cast<const f32x4*>(feat + (size_t)pids[p] * Cc + c0);
            #pragma unroll
            for (int j = 0; j < 4; ++j) f[p][j] = row[j];
        }
    }

    // Transpose: plane (c0+4j+k) gets component k of ch-quad j of each pixel.
    size_t base = ((size_t)(b * Cc + c0)) * NPIX + (size_t)q * 4;
    #pragma unroll
    for (int j = 0; j < 4; ++j) {
        #pragma unroll
        for (int k = 0; k < 4; ++k) {
            f32x4 o = { f[0][j][k], f[1][j][k], f[2][j][k], f[3][j][k] };
            __builtin_nontemporal_store(o,
                reinterpret_cast<f32x4*>(out + base + (size_t)(j * 4 + k) * NPIX));
        }
    }
}

// ---- Fallback (ws too small): memset canvas + direct scatter ----

__global__ void pps_scatter_feat(const float* __restrict__ feat,
                                 const int* __restrict__ coords,
                                 float* __restrict__ out, int n_pts) {
    int t = blockIdx.x * blockDim.x + threadIdx.x;
    int n = t >> 6;           // point id
    int c = t & 63;           // channel
    if (n >= n_pts) return;
    int bid = coords[n * 4 + 0];
    int y   = coords[n * 4 + 2];
    int x   = coords[n * 4 + 3];
    out[((size_t)(bid * Cc + c)) * NPIX + (size_t)y * NXc + x] = feat[(size_t)n * Cc + c];
}

extern "C" void kernel_launch(void* const* d_in, const int* in_sizes, int n_in,
                              void* d_out, int out_size, void* d_ws, size_t ws_size,
                              hipStream_t stream) {
    const float* feat   = (const float*)d_in[0];
    const int*   coords = (const int*)d_in[1];
    float*       out    = (float*)d_out;
    int n_pts = in_sizes[1] / 4;                 // coords is (n_pts, 4)

    size_t idx_bytes = (size_t)Bc * NPIX * sizeof(int);   // 1.71 MB

    if (ws_size >= idx_bytes) {
        int* idx = (int*)d_ws;
        pps_init_idx<<<dim3((NIDX4 + 255) / 256), dim3(256), 0, stream>>>((i32x4*)idx);
        pps_scatter_idx<<<dim3((n_pts + 255) / 256), dim3(256), 0, stream>>>(coords, idx, n_pts);
        dim3 grid((NQ + 255) / 256, (Bc * Cc) / 16);      // 210 x 8 blocks
        pps_gather16<<<grid, dim3(256), 0, stream>>>(feat, idx, out);
    } else {
        (void)hipMemsetAsync(out, 0, (size_t)out_size * sizeof(float), stream);
        long long total = (long long)n_pts * Cc;
        pps_scatter_feat<<<dim3((unsigned)((total + 255) / 256)), dim3(256), 0, stream>>>(
            feat, coords, out, n_pts);
    }
}